// Round 3
// baseline (203.906 us; speedup 1.0000x reference)
//
#include <hip/hip_runtime.h>

typedef float float4v __attribute__((ext_vector_type(4)));
typedef short short8  __attribute__((ext_vector_type(8)));

#define NBLOCKS 512          // 512 blocks * 256 tokens = 131072
#define TOK_PER_BLOCK 256    // 8 tiles of 32 tokens
#define WS_NEEDED 131072     // 16kk * 4k8g * 128ch * 16B

__device__ __forceinline__ short f2bf(float f) {
  unsigned u = __float_as_uint(f);
  return (short)((u + 0x7fffu + ((u >> 16) & 1u)) >> 16);  // RNE
}

// dk (496x128 f32) -> bf16 MFMA B-fragments in ws, K padded to 512.
// ws[(kk*4 + k8g)*128 + c] = short8{ dk_bf16[kk*32+k8g*8+j][c] : j=0..7 }
__global__ void dk_prep(const float* __restrict__ dk, short8* __restrict__ ws) {
  int g = blockIdx.x * 256 + threadIdx.x;     // 8192 total
  int c = g & 127, k8g = (g >> 7) & 3, kk = g >> 9;
  short8 t;
#pragma unroll
  for (int j = 0; j < 8; ++j) {
    int f = kk * 32 + k8g * 8 + j;
    t[j] = (f < 496) ? f2bf(dk[f * 128 + c]) : (short)0;
  }
  ws[g] = t;
}

template<bool USE_WS>
__global__ __launch_bounds__(512, 6)
void tangent_fused(const float* __restrict__ x,
                   const float* __restrict__ U0,
                   const float* __restrict__ W0,
                   const float* __restrict__ dk,
                   const short8* __restrict__ wsdk,
                   const float* __restrict__ bias,
                   float* __restrict__ out)
{
  // 50688 B total -> 3 blocks/CU (152064 <= 160 KiB); VGPR cap 85 -> 6 waves/SIMD
  // v is written IN-PLACE into xlds (v_jj at row dword 3*jj, overwriting p/q
  // after they are register-loaded); row stride 100 (== 4 mod 32 banks).
  __shared__ __align__(16) float xlds[32 * 100];
  __shared__ __align__(16) float u0p[16 * 36];
  __shared__ __align__(16) float w0p[16 * 36];
  __shared__ __align__(16) short ylds[32 * 520];   // stride 520: 65 granules == 1 mod 8

  const int tid  = threadIdx.x;
  const int lane = tid & 63;
  const int wv   = tid >> 6;          // 8 waves

  // ---- one-time: U0/W0 padded into LDS (full 576-entry zero init!) ----
  for (int i = tid; i < 576; i += 512) { u0p[i] = 0.f; w0p[i] = 0.f; }
  __syncthreads();
  if (tid < 496) {
    int r = tid / 31, c = tid % 31;
    u0p[r * 36 + c] = U0[tid];
    w0p[r * 36 + c] = W0[tid];
  }

  // ---- one-time: per-wave 16 output channels of dk as bf16 B-fragments ----
  // B layout for mfma_f32_16x16x32_bf16: lane holds B[k=(lane>>4)*8+j][n=lane&15]
  const int bn  = lane & 15;
  const int k8g = lane >> 4;
  const int k8  = k8g * 8;
  const int ch0 = wv * 16;
  short8 bfrag[16];
  if (USE_WS) {
#pragma unroll
    for (int kk = 0; kk < 16; ++kk)
      bfrag[kk] = wsdk[(kk * 4 + k8g) * 128 + ch0 + bn];
  } else {
#pragma unroll
    for (int kk = 0; kk < 16; ++kk) {
      short8 t;
#pragma unroll
      for (int j = 0; j < 8; ++j) {
        int f = kk * 32 + k8 + j;
        t[j] = (f < 496) ? f2bf(dk[f * 128 + ch0 + bn]) : (short)0;
      }
      bfrag[kk] = t;
    }
  }
  const float bias0 = bias[ch0 + bn];
  __syncthreads();

  const int trow = tid >> 4;    // token row within 32-token tile
  const int tt   = tid & 15;    // lane within 16-lane token group (same wave)
  const int block_tok0 = blockIdx.x * TOK_PER_BLOCK;

  // ---- prefetch tile 0 into registers ----
  float4v pf0, pf1;
  {
    const float4v* xg = (const float4v*)(x + (size_t)block_tok0 * 96);
    pf0 = xg[tid];
    if (tid < 256) pf1 = xg[tid + 512];
  }

  for (int tile = 0; tile < 8; ++tile) {
    const int tbase = block_tok0 + tile * 32;

    // ---- commit prefetched x tile to LDS (safe: all waves passed the
    // pre-MFMA barrier of tile-1, and MFMA only reads ylds) ----
    *(float4v*)&xlds[(tid / 24) * 100 + (tid % 24) * 4] = pf0;
    if (tid < 256) {
      int idx = tid + 512;
      *(float4v*)&xlds[(idx / 24) * 100 + (idx % 24) * 4] = pf1;
    }
    __syncthreads();   // barrier A: x visible; also orders prev MFMA vs 1b ylds writes

    // ---- issue prefetch of next tile (consumed at next commit) ----
    if (tile + 1 < 8) {
      const float4v* xg = (const float4v*)(x + (size_t)(tbase + 32) * 96);
      pf0 = xg[tid];
      if (tid < 256) pf1 = xg[tid + 512];
    }

    // ---- phase 1a: v_j = log-map, written IN-PLACE over x row ----
    {
      float* xr = &xlds[trow * 100];
      float p0 = xr[0], p1 = xr[1], p2 = xr[2];
      const int j0 = tt;            // 0..15
      const int j1 = tt + 16;       // 16..31 (31 -> pad lane)
      float a0 = xr[3 + 3 * j0], a1 = xr[4 + 3 * j0], a2 = xr[5 + 3 * j0];
      float b0 = xr[3 + 3 * j1], b1 = xr[4 + 3 * j1], b2 = xr[5 + 3 * j1];
      asm volatile("" ::: "memory");  // ALL reads precede ALL in-place writes

      // cos with np's association/rounding (acos near +-1 amplifies ulps)
      float cs0 = __fadd_rn(__fadd_rn(__fmul_rn(p0, a0), __fmul_rn(p1, a1)),
                            __fmul_rn(p2, a2));
      cs0 = fminf(fmaxf(cs0, -1.f), 1.f);
      float th0 = acosf(cs0);
      float fc0 = (th0 < 1e-6f) ? 1.f : th0 * rsqrtf((1.f - cs0) * (1.f + cs0));
      xr[3 * j0 + 0] = fc0 * (a0 - cs0 * p0);
      xr[3 * j0 + 1] = fc0 * (a1 - cs0 * p1);
      xr[3 * j0 + 2] = fc0 * (a2 - cs0 * p2);

      if (tt < 15) {
        float cs1 = __fadd_rn(__fadd_rn(__fmul_rn(p0, b0), __fmul_rn(p1, b1)),
                              __fmul_rn(p2, b2));
        cs1 = fminf(fmaxf(cs1, -1.f), 1.f);
        float th1 = acosf(cs1);
        float fc1 = (th1 < 1e-6f) ? 1.f : th1 * rsqrtf((1.f - cs1) * (1.f + cs1));
        xr[3 * j1 + 0] = fc1 * (b0 - cs1 * p0);
        xr[3 * j1 + 1] = fc1 * (b1 - cs1 * p1);
        xr[3 * j1 + 2] = fc1 * (b2 - cs1 * p2);
      } else {
        xr[93] = 0.f; xr[94] = 0.f; xr[95] = 0.f;   // j=31 pad
      }
    }
    // no barrier: 1a->1b dependency is within the 16-lane token group of one
    // wave; DS ops are in-order per wave.

    // ---- phase 1b: k/q/w for i = tt, then Y row writes (MFMA-A layout, bf16) ----
    {
      const float4v* v4 = (const float4v*)&xlds[trow * 100];
      const float4v* u4 = (const float4v*)&u0p[tt * 36];
      const float4v* w4 = (const float4v*)&w0p[tt * 36];
      float k0 = 0, k1 = 0, k2 = 0, q0 = 0, q1 = 0, q2 = 0;
#pragma unroll
      for (int g = 0; g < 8; ++g) {
        float4v a = v4[3 * g], b = v4[3 * g + 1], c = v4[3 * g + 2];
        float4v uu = u4[g], ww = w4[g];
        k0 += uu.x * a.x; k1 += uu.x * a.y; k2 += uu.x * a.z;
        q0 += ww.x * a.x; q1 += ww.x * a.y; q2 += ww.x * a.z;
        k0 += uu.y * a.w; k1 += uu.y * b.x; k2 += uu.y * b.y;
        q0 += ww.y * a.w; q1 += ww.y * b.x; q2 += ww.y * b.y;
        k0 += uu.z * b.z; k1 += uu.z * b.w; k2 += uu.z * c.x;
        q0 += ww.z * b.z; q1 += ww.z * b.w; q2 += ww.z * c.x;
        k0 += uu.w * c.y; k1 += uu.w * c.z; k2 += uu.w * c.w;
        q0 += ww.w * c.y; q1 += ww.w * c.z; q2 += ww.w * c.w;
      }
      float dot = k0 * q0 + k1 * q1 + k2 * q2;
      float sq  = k0 * k0 + k1 * k1 + k2 * k2 + 2.2204460492503131e-16f;
      float f8  = 0.8f * (fmaxf(-dot, 0.f) / sq);   // 0.2q + 0.8(q + fac*k)
      float wx = q0 + f8 * k0, wy = q1 + f8 * k1, wz = q2 + f8 * k2;

      // force re-read of v from LDS (keeping 24 float4 live would blow the
      // 85-VGPR budget needed for 6 waves/SIMD)
      asm volatile("" ::: "memory");

      short* yrow = &ylds[trow * 520];
#pragma unroll
      for (int g = 0; g < 8; ++g) {
        float4v a = v4[3 * g], b = v4[3 * g + 1], c = v4[3 * g + 2];
        float y0 = a.x * wx + a.y * wy + a.z * wz;   // jj = 4g
        float y1 = a.w * wx + b.x * wy + b.y * wz;
        float y2 = b.z * wx + b.w * wy + c.x * wz;
        float y3 = c.y * wx + c.z * wy + c.w * wz;   // g=7,r=3: v-pad -> 0
        yrow[(4 * g + 0) * 16 + tt] = f2bf(y0);
        yrow[(4 * g + 1) * 16 + tt] = f2bf(y1);
        yrow[(4 * g + 2) * 16 + tt] = f2bf(y2);
        yrow[(4 * g + 3) * 16 + tt] = f2bf(y3);
      }
    }
    __syncthreads();   // barrier B: ylds complete; MFMA may read

    // ---- phase 2: Y(32x512) @ dk(512x16ch/wave), bf16 MFMA 16x16x32 ----
    {
      const int am = lane & 15;
      float4v acc0 = {0.f, 0.f, 0.f, 0.f};
      float4v acc1 = {0.f, 0.f, 0.f, 0.f};
#pragma unroll
      for (int kk = 0; kk < 16; ++kk) {
        short8 a0 = *(const short8*)&ylds[am * 520 + kk * 32 + k8];
        short8 a1 = *(const short8*)&ylds[(16 + am) * 520 + kk * 32 + k8];
        acc0 = __builtin_amdgcn_mfma_f32_16x16x32_bf16(a0, bfrag[kk], acc0, 0, 0, 0);
        acc1 = __builtin_amdgcn_mfma_f32_16x16x32_bf16(a1, bfrag[kk], acc1, 0, 0, 0);
      }
      // C/D layout: col = lane&15, row = (lane>>4)*4 + reg
      const int row4 = k8g * 4;
#pragma unroll
      for (int r = 0; r < 4; ++r) {
        out[(size_t)(tbase + row4 + r) * 128 + ch0 + bn]      = acc0[r] + bias0;
        out[(size_t)(tbase + 16 + row4 + r) * 128 + ch0 + bn] = acc1[r] + bias0;
      }
    }
    // no trailing barrier: next tile's commit only touches xlds (1b reads of
    // xlds finished before barrier B), and barrier A orders ylds reuse.
  }
}

extern "C" void kernel_launch(void* const* d_in, const int* in_sizes, int n_in,
                              void* d_out, int out_size, void* d_ws, size_t ws_size,
                              hipStream_t stream) {
  const float* x    = (const float*)d_in[0];
  const float* U0   = (const float*)d_in[1];
  const float* W0   = (const float*)d_in[2];
  const float* dk   = (const float*)d_in[3];
  const float* bias = (const float*)d_in[4];
  float* out = (float*)d_out;
  if (ws_size >= WS_NEEDED) {
    short8* ws = (short8*)d_ws;
    dk_prep<<<32, 256, 0, stream>>>(dk, ws);
    tangent_fused<true><<<NBLOCKS, 512, 0, stream>>>(x, U0, W0, dk, ws, bias, out);
  } else {
    tangent_fused<false><<<NBLOCKS, 512, 0, stream>>>(x, U0, W0, dk, nullptr, bias, out);
  }
}

// Round 4
// 178.154 us; speedup vs baseline: 1.1446x; 1.1446x over previous
//
#include <hip/hip_runtime.h>

typedef float float4v __attribute__((ext_vector_type(4)));
typedef short short8  __attribute__((ext_vector_type(8)));

#define NBLOCKS 512          // 512 blocks * 256 tokens = 131072
#define TOK_PER_BLOCK 256    // 8 tiles of 32 tokens
#define WS_NEEDED 131072     // 16kk * 4k8g * 128ch * 16B

__device__ __forceinline__ short f2bf(float f) {
  unsigned u = __float_as_uint(f);
  return (short)((u + 0x7fffu + ((u >> 16) & 1u)) >> 16);  // RNE
}

// dk (496x128 f32) -> bf16 MFMA B-fragments in ws, K padded to 512.
// ws[(kk*4 + k8g)*128 + c] = short8{ dk_bf16[kk*32+k8g*8+j][c] : j=0..7 }
__global__ void dk_prep(const float* __restrict__ dk, short8* __restrict__ ws) {
  int g = blockIdx.x * 256 + threadIdx.x;     // 8192 total
  int c = g & 127, k8g = (g >> 7) & 3, kk = g >> 9;
  short8 t;
#pragma unroll
  for (int j = 0; j < 8; ++j) {
    int f = kk * 32 + k8g * 8 + j;
    t[j] = (f < 496) ? f2bf(dk[f * 128 + c]) : (short)0;
  }
  ws[g] = t;
}

template<bool USE_WS>
__global__ __launch_bounds__(512, 4)   // cap 128 regs: bfrag lives in AGPRs, NO spill
void tangent_fused(const float* __restrict__ x,
                   const float* __restrict__ U0,
                   const float* __restrict__ W0,
                   const float* __restrict__ dk,
                   const short8* __restrict__ wsdk,
                   const float* __restrict__ bias,
                   float* __restrict__ out)
{
  // LDS 59392 B -> 2 blocks/CU (VGPR=128 caps at 4 waves/SIMD anyway).
  // v is written IN-PLACE into xlds rows (stride 100 dw == 4 mod 32 banks).
  __shared__ __align__(16) float xlds[32 * 100];
  __shared__ __align__(16) float u0p[16 * 36];
  __shared__ __align__(16) float w0p[16 * 36];
  __shared__ __align__(16) float wlds[32 * 68];    // 16 float4 + 1 pad per token
  __shared__ __align__(16) short ylds[32 * 520];   // stride 520 sh = 260 dw == 4 mod 32

  const int tid  = threadIdx.x;
  const int lane = tid & 63;
  const int wv   = tid >> 6;          // 8 waves

  // ---- one-time: U0/W0 padded into LDS (full 576-entry zero init) ----
  for (int i = tid; i < 576; i += 512) { u0p[i] = 0.f; w0p[i] = 0.f; }
  __syncthreads();
  if (tid < 496) {
    int r = tid / 31, c = tid % 31;
    u0p[r * 36 + c] = U0[tid];
    w0p[r * 36 + c] = W0[tid];
  }

  // ---- one-time: per-wave 16 output channels of dk as bf16 B-fragments ----
  // B layout for mfma_f32_16x16x32_bf16: lane holds B[k=(lane>>4)*8+j][n=lane&15]
  const int bn  = lane & 15;
  const int k8g = lane >> 4;
  const int k8  = k8g * 8;
  const int ch0 = wv * 16;
  short8 bfrag[16];
  if (USE_WS) {
#pragma unroll
    for (int kk = 0; kk < 16; ++kk)
      bfrag[kk] = wsdk[(kk * 4 + k8g) * 128 + ch0 + bn];
  } else {
#pragma unroll
    for (int kk = 0; kk < 16; ++kk) {
      short8 t;
#pragma unroll
      for (int j = 0; j < 8; ++j) {
        int f = kk * 32 + k8 + j;
        t[j] = (f < 496) ? f2bf(dk[f * 128 + ch0 + bn]) : (short)0;
      }
      bfrag[kk] = t;
    }
  }
  const float bias0 = bias[ch0 + bn];
  __syncthreads();

  const int trow = tid >> 4;    // token row within 32-token tile
  const int tt   = tid & 15;    // lane within 16-lane token group (same wave)
  const int block_tok0 = blockIdx.x * TOK_PER_BLOCK;

  // ---- prefetch tile 0 into registers ----
  float4v pf0, pf1;
  {
    const float4v* xg = (const float4v*)(x + (size_t)block_tok0 * 96);
    pf0 = xg[tid];
    if (tid < 256) pf1 = xg[tid + 512];
  }

  for (int tile = 0; tile < 8; ++tile) {
    const int tbase = block_tok0 + tile * 32;

    // ---- commit prefetched x tile to LDS (phase-2 reads only ylds/bfrag,
    // so overwriting xlds here is safe; 1b xlds reads ended before barrier B) ----
    *(float4v*)&xlds[(tid / 24) * 100 + (tid % 24) * 4] = pf0;
    if (tid < 256) {
      int idx = tid + 512;
      *(float4v*)&xlds[(idx / 24) * 100 + (idx % 24) * 4] = pf1;
    }
    __syncthreads();   // barrier A: x visible; also orders prev MFMA vs new ylds writes

    // ---- issue prefetch of next tile (consumed at next commit) ----
    if (tile + 1 < 8) {
      const float4v* xg = (const float4v*)(x + (size_t)(tbase + 32) * 96);
      pf0 = xg[tid];
      if (tid < 256) pf1 = xg[tid + 512];
    }

    // ---- phase 1a: v_j = log-map, IN-PLACE over x row; v_{tt}, v_{tt+16}
    //      stay in registers for the y-pass ----
    float v00, v01, v02, v10, v11, v12;
    {
      float* xr = &xlds[trow * 100];
      float p0 = xr[0], p1 = xr[1], p2 = xr[2];
      const int j0 = tt;            // 0..15
      const int j1 = tt + 16;       // 16..31 (31 -> zero pad row)
      float a0 = xr[3 + 3 * j0], a1 = xr[4 + 3 * j0], a2 = xr[5 + 3 * j0];
      float b0 = xr[3 + 3 * j1], b1 = xr[4 + 3 * j1], b2 = xr[5 + 3 * j1];
      asm volatile("" ::: "memory");  // ALL reads precede ALL in-place writes

      // cos with np's association/rounding (acos near +-1 amplifies ulps)
      float cs0 = __fadd_rn(__fadd_rn(__fmul_rn(p0, a0), __fmul_rn(p1, a1)),
                            __fmul_rn(p2, a2));
      cs0 = fminf(fmaxf(cs0, -1.f), 1.f);
      float th0 = acosf(cs0);
      float fc0 = (th0 < 1e-6f) ? 1.f : th0 * rsqrtf((1.f - cs0) * (1.f + cs0));
      v00 = fc0 * (a0 - cs0 * p0);
      v01 = fc0 * (a1 - cs0 * p1);
      v02 = fc0 * (a2 - cs0 * p2);
      xr[3 * j0 + 0] = v00; xr[3 * j0 + 1] = v01; xr[3 * j0 + 2] = v02;

      if (tt < 15) {
        float cs1 = __fadd_rn(__fadd_rn(__fmul_rn(p0, b0), __fmul_rn(p1, b1)),
                              __fmul_rn(p2, b2));
        cs1 = fminf(fmaxf(cs1, -1.f), 1.f);
        float th1 = acosf(cs1);
        float fc1 = (th1 < 1e-6f) ? 1.f : th1 * rsqrtf((1.f - cs1) * (1.f + cs1));
        v10 = fc1 * (b0 - cs1 * p0);
        v11 = fc1 * (b1 - cs1 * p1);
        v12 = fc1 * (b2 - cs1 * p2);
      } else {
        v10 = 0.f; v11 = 0.f; v12 = 0.f;   // j=31: zero pad (features 496..511)
      }
      xr[3 * j1 + 0] = v10; xr[3 * j1 + 1] = v11; xr[3 * j1 + 2] = v12;
    }
    // no barrier: all xlds/wlds dependencies below are within the 16-lane
    // token group of one wave; DS ops are in-order per wave.

    // ---- phase 1b-kq: k/q for i = tt; w_tt -> wlds as float4 ----
    {
      const float4v* v4 = (const float4v*)&xlds[trow * 100];
      const float4v* u4 = (const float4v*)&u0p[tt * 36];
      const float4v* w4 = (const float4v*)&w0p[tt * 36];
      float k0 = 0, k1 = 0, k2 = 0, q0 = 0, q1 = 0, q2 = 0;
#pragma unroll
      for (int g = 0; g < 8; ++g) {
        float4v a = v4[3 * g], b = v4[3 * g + 1], c = v4[3 * g + 2];
        float4v uu = u4[g], ww = w4[g];
        k0 += uu.x * a.x; k1 += uu.x * a.y; k2 += uu.x * a.z;
        q0 += ww.x * a.x; q1 += ww.x * a.y; q2 += ww.x * a.z;
        k0 += uu.y * a.w; k1 += uu.y * b.x; k2 += uu.y * b.y;
        q0 += ww.y * a.w; q1 += ww.y * b.x; q2 += ww.y * b.y;
        k0 += uu.z * b.z; k1 += uu.z * b.w; k2 += uu.z * c.x;
        q0 += ww.z * b.z; q1 += ww.z * b.w; q2 += ww.z * c.x;
        k0 += uu.w * c.y; k1 += uu.w * c.z; k2 += uu.w * c.w;
        q0 += ww.w * c.y; q1 += ww.w * c.z; q2 += ww.w * c.w;
      }
      float dot = k0 * q0 + k1 * q1 + k2 * q2;
      float sq  = k0 * k0 + k1 * k1 + k2 * k2 + 2.2204460492503131e-16f;
      float f8  = 0.8f * (fmaxf(-dot, 0.f) / sq);   // 0.2q + 0.8(q + fac*k)
      float4v wvec = { q0 + f8 * k0, q1 + f8 * k1, q2 + f8 * k2, 0.f };
      *(float4v*)&wlds[trow * 68 + tt * 4] = wvec;
    }

    // ---- phase 1b-y: rows jj=tt and tt+16 of Y from register v's; each row
    //      written as two contiguous short8 (quad=(trow+2tt)%8: uniform, 0-conflict)
    {
      const float4v* wr = (const float4v*)&wlds[trow * 68];
      short8 r0lo, r0hi, r1lo, r1hi;
#pragma unroll
      for (int i = 0; i < 16; ++i) {
        float4v w = wr[i];
        float y0 = v00 * w.x + v01 * w.y + v02 * w.z;
        float y1 = v10 * w.x + v11 * w.y + v12 * w.z;
        if (i < 8) { r0lo[i] = f2bf(y0); r1lo[i] = f2bf(y1); }
        else       { r0hi[i - 8] = f2bf(y0); r1hi[i - 8] = f2bf(y1); }
      }
      short* yrow = &ylds[trow * 520];
      *(short8*)&yrow[tt * 16]            = r0lo;
      *(short8*)&yrow[tt * 16 + 8]        = r0hi;
      *(short8*)&yrow[(tt + 16) * 16]     = r1lo;
      *(short8*)&yrow[(tt + 16) * 16 + 8] = r1hi;
    }
    __syncthreads();   // barrier B: ylds complete; MFMA may read

    // ---- phase 2: Y(32x512) @ dk(512x16ch/wave), bf16 MFMA 16x16x32 ----
    {
      const int am = lane & 15;
      float4v acc0 = {0.f, 0.f, 0.f, 0.f};
      float4v acc1 = {0.f, 0.f, 0.f, 0.f};
#pragma unroll
      for (int kk = 0; kk < 16; ++kk) {
        short8 a0 = *(const short8*)&ylds[am * 520 + kk * 32 + k8];
        short8 a1 = *(const short8*)&ylds[(16 + am) * 520 + kk * 32 + k8];
        acc0 = __builtin_amdgcn_mfma_f32_16x16x32_bf16(a0, bfrag[kk], acc0, 0, 0, 0);
        acc1 = __builtin_amdgcn_mfma_f32_16x16x32_bf16(a1, bfrag[kk], acc1, 0, 0, 0);
      }
      // C/D layout: col = lane&15, row = (lane>>4)*4 + reg
      const int row4 = k8g * 4;
#pragma unroll
      for (int r = 0; r < 4; ++r) {
        out[(size_t)(tbase + row4 + r) * 128 + ch0 + bn]      = acc0[r] + bias0;
        out[(size_t)(tbase + 16 + row4 + r) * 128 + ch0 + bn] = acc1[r] + bias0;
      }
    }
    // no trailing barrier: next commit touches only xlds (reads done pre-B);
    // next ylds writes are ordered by barrier A.
  }
}

extern "C" void kernel_launch(void* const* d_in, const int* in_sizes, int n_in,
                              void* d_out, int out_size, void* d_ws, size_t ws_size,
                              hipStream_t stream) {
  const float* x    = (const float*)d_in[0];
  const float* U0   = (const float*)d_in[1];
  const float* W0   = (const float*)d_in[2];
  const float* dk   = (const float*)d_in[3];
  const float* bias = (const float*)d_in[4];
  float* out = (float*)d_out;
  if (ws_size >= WS_NEEDED) {
    short8* ws = (short8*)d_ws;
    dk_prep<<<32, 256, 0, stream>>>(dk, ws);
    tangent_fused<true><<<NBLOCKS, 512, 0, stream>>>(x, U0, W0, dk, ws, bias, out);
  } else {
    tangent_fused<false><<<NBLOCKS, 512, 0, stream>>>(x, U0, W0, dk, nullptr, bias, out);
  }
}

// Round 5
// 165.079 us; speedup vs baseline: 1.2352x; 1.0792x over previous
//
#include <hip/hip_runtime.h>

typedef float float4v __attribute__((ext_vector_type(4)));
typedef short short8  __attribute__((ext_vector_type(8)));

#define NBLOCKS 512          // 512 blocks * 256 tokens = 131072
#define TOK_PER_BLOCK 256    // 8 tiles of 32 tokens
#define WS_NEEDED 131072     // 16kk * 4k8g * 128ch * 16B

__device__ __forceinline__ short f2bf(float f) {
  unsigned u = __float_as_uint(f);
  return (short)((u + 0x7fffu + ((u >> 16) & 1u)) >> 16);  // RNE
}

// dk (496x128 f32) -> bf16 MFMA B-fragments in ws, K padded to 512.
// ws[(kk*4 + k8g)*128 + c] = short8{ dk_bf16[kk*32+k8g*8+j][c] : j=0..7 }
__global__ void dk_prep(const float* __restrict__ dk, short8* __restrict__ ws) {
  int g = blockIdx.x * 256 + threadIdx.x;     // 8192 total
  int c = g & 127, k8g = (g >> 7) & 3, kk = g >> 9;
  short8 t;
#pragma unroll
  for (int j = 0; j < 8; ++j) {
    int f = kk * 32 + k8g * 8 + j;
    t[j] = (f < 496) ? f2bf(dk[f * 128 + c]) : (short)0;
  }
  ws[g] = t;
}

template<bool USE_WS>
__global__ __launch_bounds__(512, 4)   // 128-reg cap: bfrag+acc in AGPRs, rest must fit
void tangent_fused(const float* __restrict__ x,
                   const float* __restrict__ U0,
                   const float* __restrict__ W0,
                   const float* __restrict__ dk,
                   const short8* __restrict__ wsdk,
                   const float* __restrict__ bias,
                   float* __restrict__ out)
{
  // LDS 59392 B -> 2 blocks/CU (VGPR=128 caps at 4 waves/SIMD anyway).
  // v is written IN-PLACE into xlds rows (stride 100 dw == 4 mod 32 banks).
  __shared__ __align__(16) float xlds[32 * 100];
  __shared__ __align__(16) float u0p[16 * 36];
  __shared__ __align__(16) float w0p[16 * 36];
  __shared__ __align__(16) float wlds[32 * 68];    // 16 float4 + 1 pad per token
  __shared__ __align__(16) short ylds[32 * 520];   // stride 520 sh = 260 dw == 4 mod 32

  const int tid  = threadIdx.x;
  const int lane = tid & 63;
  const int wv   = tid >> 6;          // 8 waves

  // ---- one-time: U0/W0 padded into LDS (full 576-entry zero init) ----
  for (int i = tid; i < 576; i += 512) { u0p[i] = 0.f; w0p[i] = 0.f; }
  __syncthreads();
  if (tid < 496) {
    int r = tid / 31, c = tid % 31;
    u0p[r * 36 + c] = U0[tid];
    w0p[r * 36 + c] = W0[tid];
  }

  // ---- one-time: per-wave 16 output channels of dk as bf16 B-fragments ----
  // B layout for mfma_f32_16x16x32_bf16: lane holds B[k=(lane>>4)*8+j][n=lane&15]
  const int bn  = lane & 15;
  const int k8g = lane >> 4;
  const int k8  = k8g * 8;
  const int ch0 = wv * 16;
  short8 bfrag[16];
  if (USE_WS) {
#pragma unroll
    for (int kk = 0; kk < 16; ++kk)
      bfrag[kk] = wsdk[(kk * 4 + k8g) * 128 + ch0 + bn];
  } else {
#pragma unroll
    for (int kk = 0; kk < 16; ++kk) {
      short8 t;
#pragma unroll
      for (int j = 0; j < 8; ++j) {
        int f = kk * 32 + k8 + j;
        t[j] = (f < 496) ? f2bf(dk[f * 128 + ch0 + bn]) : (short)0;
      }
      bfrag[kk] = t;
    }
  }
  const float bias0 = bias[ch0 + bn];
  __syncthreads();

  const int trow = tid >> 4;    // token row within 32-token tile
  const int tt   = tid & 15;    // lane within 16-lane token group (same wave)
  const int block_tok0 = blockIdx.x * TOK_PER_BLOCK;

  for (int tile = 0; tile < 8; ++tile) {
    const int tbase = block_tok0 + tile * 32;

    // ---- stage x tile (transient regs only; no cross-tile prefetch:
    // holding 8 VGPRs across the whole body caused scratch spills in R4) ----
    {
      const float4v* xg = (const float4v*)(x + (size_t)tbase * 96);
      float4v t0 = xg[tid];
      *(float4v*)&xlds[(tid / 24) * 100 + (tid % 24) * 4] = t0;
      if (tid < 256) {
        int idx = tid + 512;
        float4v t1 = xg[idx];
        *(float4v*)&xlds[(idx / 24) * 100 + (idx % 24) * 4] = t1;
      }
    }
    __syncthreads();   // barrier A: x visible; also orders prev MFMA vs new ylds writes

    // ---- phase 1a: v_j = log-map, IN-PLACE over x row; v_{tt}, v_{tt+16}
    //      stay in registers for the y-pass ----
    float v00, v01, v02, v10, v11, v12;
    {
      float* xr = &xlds[trow * 100];
      float p0 = xr[0], p1 = xr[1], p2 = xr[2];
      const int j0 = tt;            // 0..15
      const int j1 = tt + 16;       // 16..31 (31 -> zero pad row)
      float a0 = xr[3 + 3 * j0], a1 = xr[4 + 3 * j0], a2 = xr[5 + 3 * j0];
      float b0 = xr[3 + 3 * j1], b1 = xr[4 + 3 * j1], b2 = xr[5 + 3 * j1];
      asm volatile("" ::: "memory");  // ALL reads precede ALL in-place writes

      // cos with np's association/rounding (acos near +-1 amplifies ulps)
      float cs0 = __fadd_rn(__fadd_rn(__fmul_rn(p0, a0), __fmul_rn(p1, a1)),
                            __fmul_rn(p2, a2));
      cs0 = fminf(fmaxf(cs0, -1.f), 1.f);
      float th0 = acosf(cs0);
      float fc0 = (th0 < 1e-6f) ? 1.f : th0 * rsqrtf((1.f - cs0) * (1.f + cs0));
      v00 = fc0 * (a0 - cs0 * p0);
      v01 = fc0 * (a1 - cs0 * p1);
      v02 = fc0 * (a2 - cs0 * p2);
      xr[3 * j0 + 0] = v00; xr[3 * j0 + 1] = v01; xr[3 * j0 + 2] = v02;

      if (tt < 15) {
        float cs1 = __fadd_rn(__fadd_rn(__fmul_rn(p0, b0), __fmul_rn(p1, b1)),
                              __fmul_rn(p2, b2));
        cs1 = fminf(fmaxf(cs1, -1.f), 1.f);
        float th1 = acosf(cs1);
        float fc1 = (th1 < 1e-6f) ? 1.f : th1 * rsqrtf((1.f - cs1) * (1.f + cs1));
        v10 = fc1 * (b0 - cs1 * p0);
        v11 = fc1 * (b1 - cs1 * p1);
        v12 = fc1 * (b2 - cs1 * p2);
      } else {
        v10 = 0.f; v11 = 0.f; v12 = 0.f;   // j=31: zero pad (features 496..511)
      }
      xr[3 * j1 + 0] = v10; xr[3 * j1 + 1] = v11; xr[3 * j1 + 2] = v12;
    }
    // no barrier: all xlds/wlds dependencies below are within the 16-lane
    // token group of one wave; DS ops are in-order per wave.

    // ---- phase 1b-kq: k/q for i = tt; w_tt -> wlds as float4 ----
    {
      const float4v* v4 = (const float4v*)&xlds[trow * 100];
      const float4v* u4 = (const float4v*)&u0p[tt * 36];
      const float4v* w4 = (const float4v*)&w0p[tt * 36];
      float k0 = 0, k1 = 0, k2 = 0, q0 = 0, q1 = 0, q2 = 0;
#pragma unroll
      for (int g = 0; g < 8; ++g) {
        float4v a = v4[3 * g], b = v4[3 * g + 1], c = v4[3 * g + 2];
        float4v uu = u4[g], ww = w4[g];
        k0 += uu.x * a.x; k1 += uu.x * a.y; k2 += uu.x * a.z;
        q0 += ww.x * a.x; q1 += ww.x * a.y; q2 += ww.x * a.z;
        k0 += uu.y * a.w; k1 += uu.y * b.x; k2 += uu.y * b.y;
        q0 += ww.y * a.w; q1 += ww.y * b.x; q2 += ww.y * b.y;
        k0 += uu.z * b.z; k1 += uu.z * b.w; k2 += uu.z * c.x;
        q0 += ww.z * b.z; q1 += ww.z * b.w; q2 += ww.z * c.x;
        k0 += uu.w * c.y; k1 += uu.w * c.z; k2 += uu.w * c.w;
        q0 += ww.w * c.y; q1 += ww.w * c.z; q2 += ww.w * c.w;
      }
      float dot = k0 * q0 + k1 * q1 + k2 * q2;
      float sq  = k0 * k0 + k1 * k1 + k2 * k2 + 2.2204460492503131e-16f;
      float f8  = 0.8f * (fmaxf(-dot, 0.f) / sq);   // 0.2q + 0.8(q + fac*k)
      float4v wvec = { q0 + f8 * k0, q1 + f8 * k1, q2 + f8 * k2, 0.f };
      *(float4v*)&wlds[trow * 68 + tt * 4] = wvec;
    }

    // ---- phase 1b-y: rows jj=tt and tt+16 of Y from register v's; two
    //      half-passes of 8 w's so only 2 short8 temps are live at once ----
    {
      const float4v* wr = (const float4v*)&wlds[trow * 68];
      short* yrow = &ylds[trow * 520];
      short8 r0, r1;
#pragma unroll
      for (int i = 0; i < 8; ++i) {
        float4v w = wr[i];
        r0[i] = f2bf(v00 * w.x + v01 * w.y + v02 * w.z);
        r1[i] = f2bf(v10 * w.x + v11 * w.y + v12 * w.z);
      }
      *(short8*)&yrow[tt * 16]        = r0;
      *(short8*)&yrow[(tt + 16) * 16] = r1;
#pragma unroll
      for (int i = 8; i < 16; ++i) {
        float4v w = wr[i];
        r0[i - 8] = f2bf(v00 * w.x + v01 * w.y + v02 * w.z);
        r1[i - 8] = f2bf(v10 * w.x + v11 * w.y + v12 * w.z);
      }
      *(short8*)&yrow[tt * 16 + 8]        = r0;
      *(short8*)&yrow[(tt + 16) * 16 + 8] = r1;
    }
    __syncthreads();   // barrier B: ylds complete; MFMA may read

    // ---- phase 2: Y(32x512) @ dk(512x16ch/wave), bf16 MFMA 16x16x32 ----
    {
      const int am = lane & 15;
      float4v acc0 = {0.f, 0.f, 0.f, 0.f};
      float4v acc1 = {0.f, 0.f, 0.f, 0.f};
#pragma unroll
      for (int kk = 0; kk < 16; ++kk) {
        short8 a0 = *(const short8*)&ylds[am * 520 + kk * 32 + k8];
        short8 a1 = *(const short8*)&ylds[(16 + am) * 520 + kk * 32 + k8];
        acc0 = __builtin_amdgcn_mfma_f32_16x16x32_bf16(a0, bfrag[kk], acc0, 0, 0, 0);
        acc1 = __builtin_amdgcn_mfma_f32_16x16x32_bf16(a1, bfrag[kk], acc1, 0, 0, 0);
      }
      // C/D layout: col = lane&15, row = (lane>>4)*4 + reg
      const int row4 = k8g * 4;
#pragma unroll
      for (int r = 0; r < 4; ++r) {
        out[(size_t)(tbase + row4 + r) * 128 + ch0 + bn]      = acc0[r] + bias0;
        out[(size_t)(tbase + 16 + row4 + r) * 128 + ch0 + bn] = acc1[r] + bias0;
      }
    }
    // no trailing barrier: next commit touches only xlds (reads done pre-B);
    // next ylds writes are ordered by barrier A.
  }
}

extern "C" void kernel_launch(void* const* d_in, const int* in_sizes, int n_in,
                              void* d_out, int out_size, void* d_ws, size_t ws_size,
                              hipStream_t stream) {
  const float* x    = (const float*)d_in[0];
  const float* U0   = (const float*)d_in[1];
  const float* W0   = (const float*)d_in[2];
  const float* dk   = (const float*)d_in[3];
  const float* bias = (const float*)d_in[4];
  float* out = (float*)d_out;
  if (ws_size >= WS_NEEDED) {
    short8* ws = (short8*)d_ws;
    dk_prep<<<32, 256, 0, stream>>>(dk, ws);
    tangent_fused<true><<<NBLOCKS, 512, 0, stream>>>(x, U0, W0, dk, ws, bias, out);
  } else {
    tangent_fused<false><<<NBLOCKS, 512, 0, stream>>>(x, U0, W0, dk, nullptr, bias, out);
  }
}